// Round 15
// baseline (257.159 us; speedup 1.0000x reference)
//
#include <hip/hip_runtime.h>

#define NPTS 8192
#define DIM 128
#define NCLS 128
#define KSEL 17      // k+1 smallest define the threshold
#define ROWS 32      // rows per block (two 16-row MFMA sets)
#define CGN 8        // column groups (1024 cols each; 256 per wave)
#define CAPW 40      // per-(wave,row) LDS candidate capacity
#define SEG  32      // per-(row,cg) scratch segment
#define NT   16      // tiles per wave (256 cols / 16)
#define MBLK 512     // merge blocks
#define BIG 3.0e38f

typedef short bf16x8 __attribute__((ext_vector_type(8)));
typedef float f32x4 __attribute__((ext_vector_type(4)));

__device__ __forceinline__ unsigned short f2bf(float f) {
  unsigned int u = __float_as_uint(f);
  u += 0x7fffu + ((u >> 16) & 1u);   // round-to-nearest-even
  return (unsigned short)(u >> 16);
}

// order-preserving float <-> uint map (total order, exact inverse)
__device__ __forceinline__ unsigned flipF(float f) {
  unsigned u = __float_as_uint(f);
  return (u & 0x80000000u) ? ~u : (u | 0x80000000u);
}
__device__ __forceinline__ float unflipF(unsigned k) {
  unsigned u = (k & 0x80000000u) ? (k & 0x7fffffffu) : ~k;
  return __uint_as_float(u);
}

// exact KSEL-th smallest of the 128 values {a,b} x 64 lanes (ballot radix descent)
__device__ __forceinline__ float kth17_2(float a, float b) {
  const unsigned ka = flipF(a), kb = flipF(b);
  unsigned ans = 0;
  for (int bit = 31; bit >= 0; --bit) {
    unsigned mid = ans | (1u << bit);
    int c = __popcll(__ballot(ka < mid)) + __popcll(__ballot(kb < mid));
    if (c < KSEL) ans = mid;
  }
  return unflipF(ans);   // largest v with count(<v) < KSEL == KSEL-th smallest
}
// exact KSEL-th smallest over 256 values (4/lane)
__device__ __forceinline__ float kth17_4(float a, float b, float c_, float d) {
  const unsigned ka = flipF(a), kb = flipF(b), kc = flipF(c_), kd = flipF(d);
  unsigned ans = 0;
  for (int bit = 31; bit >= 0; --bit) {
    unsigned mid = ans | (1u << bit);
    int c = __popcll(__ballot(ka < mid)) + __popcll(__ballot(kb < mid)) +
            __popcll(__ballot(kc < mid)) + __popcll(__ballot(kd < mid));
    if (c < KSEL) ans = mid;
  }
  return unflipF(ans);
}

// ---- prep: blocks 0..2047 build bf16 X + exact norms; block 2048: class stats (LDS,
// vectorized 4-wide target loads).
__global__ void prep(const float* __restrict__ X, const long long* __restrict__ targets,
                     unsigned short* __restrict__ Xb, float* __restrict__ sqv,
                     int* __restrict__ tgt, int* __restrict__ ccount,
                     int* __restrict__ j0a, int* __restrict__ j1a) {
  const int tid = threadIdx.x;
  if (blockIdx.x == 2048) {
    __shared__ int cc[NCLS], c0[NCLS], c1[NCLS];
    if (tid < NCLS) { cc[tid] = 0; c0[tid] = 0x7fffffff; c1[tid] = 0x7fffffff; }
    __syncthreads();
    for (int base = tid * 4; base < NPTS; base += 1024) {
      const long long* p = targets + base;
#pragma unroll
      for (int k = 0; k < 4; k++) {
        int c = (int)p[k];
        tgt[base + k] = c;
        atomicAdd(&cc[c], 1);
        atomicMin(&c0[c], base + k);
      }
    }
    __syncthreads();
    for (int base = tid * 4; base < NPTS; base += 1024) {
#pragma unroll
      for (int k = 0; k < 4; k++) {
        int c = tgt[base + k];
        if (base + k != c0[c]) atomicMin(&c1[c], base + k);
      }
    }
    __syncthreads();
    if (tid < NCLS) { ccount[tid] = cc[tid]; j0a[tid] = c0[tid]; j1a[tid] = c1[tid]; }
    return;
  }
  const int w = tid >> 6, lane = tid & 63;
  const int gw = blockIdx.x * 4 + w;
  const float* xr = X + (size_t)gw * DIM;
  float a = xr[lane], b = xr[lane + 64];
  Xb[(size_t)gw * DIM + lane] = f2bf(a);
  Xb[(size_t)gw * DIM + lane + 64] = f2bf(b);
  float s = a * a + b * b;
#pragma unroll
  for (int off = 32; off; off >>= 1) s += __shfl_xor(s, off);
  if (lane == 0) sqv[gw] = s;
}

// ---- two-sweep kNN: grid 2048 = 256 row-groups(32 rows) x 8 column-groups.
// Wave w scans cols [cg*1024 + w*256, +256), two MFMA accumulator chains,
// register double-buffer depth-1. val = sqj - 2*G (sqi-invariant ordering per row).
__global__ __launch_bounds__(256, 4) void knn_main(
    const unsigned short* __restrict__ Xb, const float* __restrict__ sqv,
    const int* __restrict__ tgt, float* __restrict__ scr, int* __restrict__ cscr) {
  __shared__ float sh[5120];   // union: cand[32][128] (16KB) / bufD[4][32][CAPW] (20KB)
  __shared__ int   cnt[4][ROWS];
  __shared__ float Uv[ROWS];

  const int tid = threadIdx.x;
  const int w = tid >> 6;
  const int lane = tid & 63;
  const int quad = lane >> 4;
  const int l16 = lane & 15;
  const int rg = blockIdx.x >> 3;
  const int cg = blockIdx.x & 7;
  const int rbase = rg * ROWS;
  const int colbase = cg * 1024 + w * 256;

  // A fragments: 2 sets x K=128. 16x16x32 bf16: A[m=lane&15][k=quad*8+j]
  bf16x8 afrag[2][4];
#pragma unroll
  for (int s = 0; s < 2; s++) {
    const unsigned short* arow = Xb + (size_t)(rbase + s * 16 + l16) * DIM + quad * 8;
#pragma unroll
    for (int kb = 0; kb < 4; kb++) afrag[s][kb] = *(const bf16x8*)(arow + kb * 32);
  }
  float sqi[2][4]; int ti[2][4];
#pragma unroll
  for (int s = 0; s < 2; s++)
#pragma unroll
    for (int r = 0; r < 4; r++) {
      int rr = rbase + s * 16 + quad * 4 + r;
      sqi[s][r] = sqv[rr]; ti[s][r] = tgt[rr];
    }

  // wave-uniform diagonal tile per set (or -1)
  int tdiag[2];
#pragma unroll
  for (int s = 0; s < 2; s++) {
    int d = rbase + s * 16 - colbase;
    tdiag[s] = (d >= 0 && d < 256) ? (d >> 4) : -1;
  }

  const unsigned short* bbase = Xb + (size_t)(colbase + l16) * DIM + quad * 8;
  const float* sqp = sqv + colbase + l16;
  const int*   tgp = tgt + colbase + l16;

  // ---- sweep 1: per-lane two smallest vals per row; register double-buffered
  float m1[2][4], m2[2][4];
#pragma unroll
  for (int s = 0; s < 2; s++)
#pragma unroll
    for (int r = 0; r < 4; r++) { m1[s][r] = BIG; m2[s][r] = BIG; }
  {
    bf16x8 bA[4], bB[4]; float sqA, sqB;
#pragma unroll
    for (int kb = 0; kb < 4; kb++) bA[kb] = *(const bf16x8*)(bbase + kb * 32);
    sqA = sqp[0];
    for (int t = 0; t < NT; t += 2) {
      {
        const unsigned short* p = bbase + (size_t)(t + 1) * (16 * DIM);
#pragma unroll
        for (int kb = 0; kb < 4; kb++) bB[kb] = *(const bf16x8*)(p + kb * 32);
        sqB = sqp[(t + 1) * 16];
      }
      {
        f32x4 a0 = {0.f,0.f,0.f,0.f}, a1 = {0.f,0.f,0.f,0.f};
#pragma unroll
        for (int kb = 0; kb < 4; kb++) {
          a0 = __builtin_amdgcn_mfma_f32_16x16x32_bf16(afrag[0][kb], bA[kb], a0, 0, 0, 0);
          a1 = __builtin_amdgcn_mfma_f32_16x16x32_bf16(afrag[1][kb], bA[kb], a1, 0, 0, 0);
        }
#pragma unroll
        for (int s = 0; s < 2; s++) {
#pragma unroll
          for (int r = 0; r < 4; r++) {
            float v = fmaf(-2.0f, (s ? a1[r] : a0[r]), sqA);
            if (t == tdiag[s] && l16 == quad * 4 + r) v = BIG;
            m2[s][r] = fminf(m2[s][r], fmaxf(m1[s][r], v));
            m1[s][r] = fminf(m1[s][r], v);
          }
        }
      }
      {
        const int tn = (t + 2 < NT) ? t + 2 : NT - 1;
        const unsigned short* p = bbase + (size_t)tn * (16 * DIM);
#pragma unroll
        for (int kb = 0; kb < 4; kb++) bA[kb] = *(const bf16x8*)(p + kb * 32);
        sqA = sqp[tn * 16];
      }
      {
        f32x4 a0 = {0.f,0.f,0.f,0.f}, a1 = {0.f,0.f,0.f,0.f};
#pragma unroll
        for (int kb = 0; kb < 4; kb++) {
          a0 = __builtin_amdgcn_mfma_f32_16x16x32_bf16(afrag[0][kb], bB[kb], a0, 0, 0, 0);
          a1 = __builtin_amdgcn_mfma_f32_16x16x32_bf16(afrag[1][kb], bB[kb], a1, 0, 0, 0);
        }
#pragma unroll
        for (int s = 0; s < 2; s++) {
#pragma unroll
          for (int r = 0; r < 4; r++) {
            float v = fmaf(-2.0f, (s ? a1[r] : a0[r]), sqB);
            if (t + 1 == tdiag[s] && l16 == quad * 4 + r) v = BIG;
            m2[s][r] = fminf(m2[s][r], fmaxf(m1[s][r], v));
            m1[s][r] = fminf(m1[s][r], v);
          }
        }
      }
    }
  }
  // publish min2: per row 4 waves x 16 lanes x 2 = 128 candidates (val-space)
#pragma unroll
  for (int s = 0; s < 2; s++)
#pragma unroll
    for (int r = 0; r < 4; r++) {
      int row = s * 16 + quad * 4 + r;
      sh[row * 128 + w * 32 + l16 * 2] = m1[s][r];
      sh[row * 128 + w * 32 + l16 * 2 + 1] = m2[s][r];
    }
  __syncthreads();

  // U[row] = 17th smallest of the 128-candidate subset (radix-select; >= group t17)
  for (int ri = 0; ri < 8; ri++) {
    int row = w * 8 + ri;
    float v17 = kth17_2(sh[row * 128 + lane], sh[row * 128 + 64 + lane]);
    if (lane == 0) Uv[row] = v17;
  }
  __syncthreads();
  float Ur[2][4];
#pragma unroll
  for (int s = 0; s < 2; s++)
#pragma unroll
    for (int r = 0; r < 4; r++) Ur[s][r] = Uv[s * 16 + quad * 4 + r];
  if (lane < ROWS) cnt[w][lane] = 0;   // wave-local; ordered before this wave's appends

  // ---- sweep 2: append val <= U (encode d2 = val + sqi, flag in sign bit)
  {
    bf16x8 bA[4], bB[4]; float sqA, sqB; int tjA, tjB;
#pragma unroll
    for (int kb = 0; kb < 4; kb++) bA[kb] = *(const bf16x8*)(bbase + kb * 32);
    sqA = sqp[0]; tjA = tgp[0];
    for (int t = 0; t < NT; t += 2) {
      {
        const unsigned short* p = bbase + (size_t)(t + 1) * (16 * DIM);
#pragma unroll
        for (int kb = 0; kb < 4; kb++) bB[kb] = *(const bf16x8*)(p + kb * 32);
        sqB = sqp[(t + 1) * 16]; tjB = tgp[(t + 1) * 16];
      }
      {
        f32x4 a0 = {0.f,0.f,0.f,0.f}, a1 = {0.f,0.f,0.f,0.f};
#pragma unroll
        for (int kb = 0; kb < 4; kb++) {
          a0 = __builtin_amdgcn_mfma_f32_16x16x32_bf16(afrag[0][kb], bA[kb], a0, 0, 0, 0);
          a1 = __builtin_amdgcn_mfma_f32_16x16x32_bf16(afrag[1][kb], bA[kb], a1, 0, 0, 0);
        }
        float vv[2][4]; bool any = false;
#pragma unroll
        for (int s = 0; s < 2; s++)
#pragma unroll
          for (int r = 0; r < 4; r++) {
            float v = fmaf(-2.0f, (s ? a1[r] : a0[r]), sqA);
            if (t == tdiag[s] && l16 == quad * 4 + r) v = BIG;
            vv[s][r] = v; any |= (v <= Ur[s][r]);
          }
        if (__any(any)) {
#pragma unroll
          for (int s = 0; s < 2; s++)
#pragma unroll
            for (int r = 0; r < 4; r++) {
              if (vv[s][r] <= Ur[s][r]) {
                int rl = s * 16 + quad * 4 + r;
                int pos = atomicAdd(&cnt[w][rl], 1);
                if (pos < CAPW) {
                  unsigned enc = __float_as_uint(fmaxf(vv[s][r] + sqi[s][r], 0.0f));
                  if (tjA == ti[s][r]) enc |= 0x80000000u;
                  sh[(w * ROWS + rl) * CAPW + pos] = __uint_as_float(enc);
                }
              }
            }
        }
      }
      {
        const int tn = (t + 2 < NT) ? t + 2 : NT - 1;
        const unsigned short* p = bbase + (size_t)tn * (16 * DIM);
#pragma unroll
        for (int kb = 0; kb < 4; kb++) bA[kb] = *(const bf16x8*)(p + kb * 32);
        sqA = sqp[tn * 16]; tjA = tgp[tn * 16];
      }
      {
        f32x4 a0 = {0.f,0.f,0.f,0.f}, a1 = {0.f,0.f,0.f,0.f};
#pragma unroll
        for (int kb = 0; kb < 4; kb++) {
          a0 = __builtin_amdgcn_mfma_f32_16x16x32_bf16(afrag[0][kb], bB[kb], a0, 0, 0, 0);
          a1 = __builtin_amdgcn_mfma_f32_16x16x32_bf16(afrag[1][kb], bB[kb], a1, 0, 0, 0);
        }
        float vv[2][4]; bool any = false;
#pragma unroll
        for (int s = 0; s < 2; s++)
#pragma unroll
          for (int r = 0; r < 4; r++) {
            float v = fmaf(-2.0f, (s ? a1[r] : a0[r]), sqB);
            if (t + 1 == tdiag[s] && l16 == quad * 4 + r) v = BIG;
            vv[s][r] = v; any |= (v <= Ur[s][r]);
          }
        if (__any(any)) {
#pragma unroll
          for (int s = 0; s < 2; s++)
#pragma unroll
            for (int r = 0; r < 4; r++) {
              if (vv[s][r] <= Ur[s][r]) {
                int rl = s * 16 + quad * 4 + r;
                int pos = atomicAdd(&cnt[w][rl], 1);
                if (pos < CAPW) {
                  unsigned enc = __float_as_uint(fmaxf(vv[s][r] + sqi[s][r], 0.0f));
                  if (tjB == ti[s][r]) enc |= 0x80000000u;
                  sh[(w * ROWS + rl) * CAPW + pos] = __uint_as_float(enc);
                }
              }
            }
        }
      }
    }
  }
  __syncthreads();

  // ---- finalize: raw-copy candidate lists (common) or 17-extract (overflow, rare)
  for (int rl = 0; rl < ROWS; rl++) {
    const int c0 = min(cnt[0][rl], CAPW), c1 = min(cnt[1][rl], CAPW),
              c2 = min(cnt[2][rl], CAPW), c3 = min(cnt[3][rl], CAPW);
    const int tot = c0 + c1 + c2 + c3;
    const int grow = rbase + rl;
    float* srow = scr + (size_t)grow * (CGN * SEG) + cg * SEG;
    if (tot <= SEG) {
      const int pre = (w > 0 ? c0 : 0) + (w > 1 ? c1 : 0) + (w > 2 ? c2 : 0);
      const int myc = (w == 0) ? c0 : ((w == 1) ? c1 : ((w == 2) ? c2 : c3));
      if (lane < myc) srow[pre + lane] = sh[(w * ROWS + rl) * CAPW + lane];
      if (tid == 0) cscr[grow * CGN + cg] = tot;
    } else if (w == (rl & 3)) {
      float e[4]; int m[4];
#pragma unroll
      for (int ww = 0; ww < 4; ww++) {
        int n = min(cnt[ww][rl], CAPW);
        if (lane < n) {
          unsigned u = __float_as_uint(sh[(ww * ROWS + rl) * CAPW + lane]);
          m[ww] = (int)(u >> 31); e[ww] = __uint_as_float(u & 0x7fffffffu);
        } else { e[ww] = BIG; m[ww] = 0; }
      }
      for (int round = 0; round < KSEL; round++) {
        float v = e[0]; int idx = lane;
        if (e[1] < v) { v = e[1]; idx = lane | (1 << 6); }
        if (e[2] < v) { v = e[2]; idx = lane | (2 << 6); }
        if (e[3] < v) { v = e[3]; idx = lane | (3 << 6); }
#pragma unroll
        for (int off = 32; off; off >>= 1) {
          float ov = __shfl_xor(v, off);
          int   oi = __shfl_xor(idx, off);
          if (ov < v || (ov == v && oi < idx)) { v = ov; idx = oi; }
        }
        if ((idx & 63) == lane) {
          int s = idx >> 6;
          unsigned ub = __float_as_uint(e[s]);
          if (m[s]) ub |= 0x80000000u;
          srow[round] = __uint_as_float(ub);
          e[s] = BIG;
        }
      }
      if (lane == 0) cscr[grow * CGN + cg] = KSEL;
    }
  }
}

// ---- per-row merge of 8 segment-lists (<=256 candidates, 4/lane) + loss epilogue.
// NO fences, NO global atomics: per-block partials to pacc (plain stores).
__global__ __launch_bounds__(256) void knn_merge(
    const float* __restrict__ scr, const int* __restrict__ cscr,
    const float* __restrict__ sqv, const int* __restrict__ tgt,
    const int* __restrict__ ccount, const int* __restrict__ j0a,
    const int* __restrict__ j1a, const float* __restrict__ X32,
    float* __restrict__ pacc) {
  __shared__ float blockAcc[4];
  const int tid = threadIdx.x;
  const int w = tid >> 6;
  const int lane = tid & 63;
  if (tid < 4) blockAcc[tid] = 0.0f;
  __syncthreads();
  for (int ri = 0; ri < 4; ri++) {
    const int grow = blockIdx.x * 16 + w * 4 + ri;
    const float* srow = scr + (size_t)grow * (CGN * SEG);
    const int cnt8 = (lane < CGN) ? cscr[grow * CGN + lane] : 0;
    float e[4]; int m[4];
#pragma unroll
    for (int k = 0; k < 4; k++) {
      const int s = lane + 64 * k;               // 0..255 = CGN*SEG slots
      const int ck = __shfl(cnt8, s >> 5);       // count for segment s/32
      if ((s & 31) < ck) {
        unsigned u = __float_as_uint(srow[s]);
        m[k] = (int)(u >> 31); e[k] = __uint_as_float(u & 0x7fffffffu);
      } else { e[k] = BIG; m[k] = 0; }
    }
    const float t17 = kth17_4(e[0], e[1], e[2], e[3]);   // exact union 17th
    float pls = 0.f, nls = 0.f; int cpn = 0;
#pragma unroll
    for (int k = 0; k < 4; k++) {
      if (e[k] < t17) {                          // strict, matches reference
        float ex = expf(-sqrtf(fmaxf(e[k], 1e-12f)));
        if (m[k]) { pls += ex; cpn += 65536; } else { nls += ex; cpn += 1; }
      }
    }
#pragma unroll
    for (int off = 32; off; off >>= 1) {
      pls += __shfl_xor(pls, off); nls += __shfl_xor(nls, off);
      cpn += __shfl_xor(cpn, off);
    }
    const int cp = cpn >> 16, cn = cpn & 0xffff;
    const int c = tgt[grow];
    const int ncl = ccount[c];
    const bool valid = (ncl > 1) && (ncl < NPTS);
    if (valid) {
      float pos_eff;
      if (cp == 0) {
        const int jf = (grow == j0a[c]) ? j1a[c] : j0a[c];
        const float* xi = X32 + (size_t)grow * DIM;
        const float* xj = X32 + (size_t)jf * DIM;
        float pp = xi[lane] * xj[lane] + xi[lane + 64] * xj[lane + 64];
#pragma unroll
        for (int off = 32; off; off >>= 1) pp += __shfl_xor(pp, off);
        const float fb2 = sqv[grow] + sqv[jf] - 2.0f * pp;
        pos_eff = expf(-sqrtf(fmaxf(fb2, 1e-12f)));
      } else {
        pos_eff = pls;
      }
      if (lane == 0) {
        const float loss_i = -logf(pos_eff / (pos_eff + nls));
        const int cpa = (cp == 0) ? 1 : cp;
        atomicAdd(&blockAcc[0], loss_i);
        atomicAdd(&blockAcc[1], (cpa > cn) ? 1.0f : 0.0f);
        atomicAdd(&blockAcc[2], (float)cp);
        atomicAdd(&blockAcc[3], (float)cn);
      }
    }
  }
  __syncthreads();
  if (tid < 4) pacc[blockIdx.x * 4 + tid] = blockAcc[tid];
}

// ---- final reduction: 1 block sums 512 x 4 partials, writes out
__global__ void fin(const float* __restrict__ pacc, float* __restrict__ out) {
  __shared__ float red[256];
  const int tid = threadIdx.x;
  const int c = tid & 3, b0 = tid >> 2;
  float s = 0.0f;
  for (int b = b0; b < MBLK; b += 64) s += pacc[b * 4 + c];
  red[tid] = s;
  __syncthreads();
  if (tid < 4) {
    float t = 0.0f;
    for (int i = tid; i < 256; i += 4) t += red[i];
    out[tid] = t * (1.0f / (float)NPTS);
  }
}

extern "C" void kernel_launch(void* const* d_in, const int* in_sizes, int n_in,
                              void* d_out, int out_size, void* d_ws, size_t ws_size,
                              hipStream_t stream) {
  const float* X = (const float*)d_in[0];
  const long long* targets = (const long long*)d_in[1];
  float* out = (float*)d_out;

  char* ws = (char*)d_ws;
  unsigned short* Xb = (unsigned short*)ws;                        // 2 MiB
  float* sqv    = (float*)   (ws + (2u << 20));                    // 32 KiB
  int*   tgt    = (int*)     (ws + (2u << 20) + (32u << 10));      // 32 KiB
  int*   ccount = (int*)     (ws + (2u << 20) + (64u << 10));      // 512 B
  int*   j0a    = (int*)     (ws + (2u << 20) + (65u << 10));      // 512 B
  int*   j1a    = (int*)     (ws + (2u << 20) + (66u << 10));      // 512 B
  float* pacc   = (float*)   (ws + (2u << 20) + (68u << 10));      // 8 KiB (512 x 4)
  float* scr = (float*)(ws + (2u << 20) + (128u << 10));           // 8192*8*SEG*4 = 8 MiB
  int* cscr  = (int*)  (ws + (2u << 20) + (128u << 10) + (size_t)NPTS * CGN * SEG * 4); // 256 KiB

  prep<<<2049, 256, 0, stream>>>(X, targets, Xb, sqv, tgt, ccount, j0a, j1a);
  knn_main<<<2048, 256, 0, stream>>>(Xb, sqv, tgt, scr, cscr);
  knn_merge<<<MBLK, 256, 0, stream>>>(scr, cscr, sqv, tgt, ccount, j0a, j1a, X, pacc);
  fin<<<1, 256, 0, stream>>>(pacc, out);
}

// Round 16
// 225.492 us; speedup vs baseline: 1.1404x; 1.1404x over previous
//
#include <hip/hip_runtime.h>

#define NPTS 8192
#define DIM 128
#define NCLS 128
#define KSEL 17      // k+1 smallest define the threshold
#define ROWS 32      // rows per block (two 16-row MFMA sets)
#define CAPW 40      // per-(wave,row) LDS candidate capacity
#define SEG  32      // per-(row,quarter) scratch segment
#define NT   32      // tiles per wave (512 cols / 16)
#define MBLK 512     // merge blocks
#define BIG 3.0e38f

typedef short bf16x8 __attribute__((ext_vector_type(8)));
typedef float f32x4 __attribute__((ext_vector_type(4)));

__device__ __forceinline__ unsigned short f2bf(float f) {
  unsigned int u = __float_as_uint(f);
  u += 0x7fffu + ((u >> 16) & 1u);   // round-to-nearest-even
  return (unsigned short)(u >> 16);
}

// order-preserving float <-> uint map (total order, exact inverse)
__device__ __forceinline__ unsigned flipF(float f) {
  unsigned u = __float_as_uint(f);
  return (u & 0x80000000u) ? ~u : (u | 0x80000000u);
}
__device__ __forceinline__ float unflipF(unsigned k) {
  unsigned u = (k & 0x80000000u) ? (k & 0x7fffffffu) : ~k;
  return __uint_as_float(u);
}

// exact KSEL-th smallest of the 128 values {a,b} x 64 lanes (ballot radix descent)
__device__ __forceinline__ float kth17_2(float a, float b) {
  const unsigned ka = flipF(a), kb = flipF(b);
  unsigned ans = 0;
  for (int bit = 31; bit >= 0; --bit) {
    unsigned mid = ans | (1u << bit);
    int c = __popcll(__ballot(ka < mid)) + __popcll(__ballot(kb < mid));
    if (c < KSEL) ans = mid;
  }
  return unflipF(ans);   // largest v with count(<v) < KSEL == KSEL-th smallest
}

// ---- prep: blocks 0..2047 build bf16 X + exact norms; block 2048: class stats (LDS,
// vectorized 4-wide target loads).
__global__ void prep(const float* __restrict__ X, const long long* __restrict__ targets,
                     unsigned short* __restrict__ Xb, float* __restrict__ sqv,
                     int* __restrict__ tgt, int* __restrict__ ccount,
                     int* __restrict__ j0a, int* __restrict__ j1a) {
  const int tid = threadIdx.x;
  if (blockIdx.x == 2048) {
    __shared__ int cc[NCLS], c0[NCLS], c1[NCLS];
    if (tid < NCLS) { cc[tid] = 0; c0[tid] = 0x7fffffff; c1[tid] = 0x7fffffff; }
    __syncthreads();
    for (int base = tid * 4; base < NPTS; base += 1024) {
      const long long* p = targets + base;
#pragma unroll
      for (int k = 0; k < 4; k++) {
        int c = (int)p[k];
        tgt[base + k] = c;
        atomicAdd(&cc[c], 1);
        atomicMin(&c0[c], base + k);
      }
    }
    __syncthreads();
    for (int base = tid * 4; base < NPTS; base += 1024) {
#pragma unroll
      for (int k = 0; k < 4; k++) {
        int c = tgt[base + k];
        if (base + k != c0[c]) atomicMin(&c1[c], base + k);
      }
    }
    __syncthreads();
    if (tid < NCLS) { ccount[tid] = cc[tid]; j0a[tid] = c0[tid]; j1a[tid] = c1[tid]; }
    return;
  }
  const int w = tid >> 6, lane = tid & 63;
  const int gw = blockIdx.x * 4 + w;
  const float* xr = X + (size_t)gw * DIM;
  float a = xr[lane], b = xr[lane + 64];
  Xb[(size_t)gw * DIM + lane] = f2bf(a);
  Xb[(size_t)gw * DIM + lane + 64] = f2bf(b);
  float s = a * a + b * b;
#pragma unroll
  for (int off = 32; off; off >>= 1) s += __shfl_xor(s, off);
  if (lane == 0) sqv[gw] = s;
}

// ---- two-sweep kNN: grid 1024 = 256 row-groups(32 rows) x 4 column-quarters.
// Wave w scans cols [quarter*2048 + w*512, +512); per iteration TWO 16-col tiles are
// loaded together (10 independent loads in flight) then consumed by 16 MFMAs +
// 2 epilogues — halves the number of memory-stall windows per wave vs tile-at-a-time.
// val = sqj - 2*G (sqi-invariant ordering per row).
__global__ __launch_bounds__(256, 3) void knn_main(
    const unsigned short* __restrict__ Xb, const float* __restrict__ sqv,
    const int* __restrict__ tgt, float* __restrict__ scr, int* __restrict__ cscr) {
  __shared__ float sh[5120];   // union: cand[32][128] (16KB) / bufD[4][32][CAPW] (20KB)
  __shared__ int   cnt[4][ROWS];
  __shared__ float Uv[ROWS];

  const int tid = threadIdx.x;
  const int w = tid >> 6;
  const int lane = tid & 63;
  const int quad = lane >> 4;
  const int l16 = lane & 15;
  const int rg = blockIdx.x >> 2;
  const int quarter = blockIdx.x & 3;
  const int rbase = rg * ROWS;
  const int colbase = quarter * 2048 + w * 512;

  // A fragments: 2 sets x K=128. 16x16x32 bf16: A[m=lane&15][k=quad*8+j]
  bf16x8 afrag[2][4];
#pragma unroll
  for (int s = 0; s < 2; s++) {
    const unsigned short* arow = Xb + (size_t)(rbase + s * 16 + l16) * DIM + quad * 8;
#pragma unroll
    for (int kb = 0; kb < 4; kb++) afrag[s][kb] = *(const bf16x8*)(arow + kb * 32);
  }
  float sqi[2][4]; int ti[2][4];
#pragma unroll
  for (int s = 0; s < 2; s++)
#pragma unroll
    for (int r = 0; r < 4; r++) {
      int rr = rbase + s * 16 + quad * 4 + r;
      sqi[s][r] = sqv[rr]; ti[s][r] = tgt[rr];
    }

  // wave-uniform diagonal tile per set (or -1)
  int tdiag[2];
#pragma unroll
  for (int s = 0; s < 2; s++) {
    int d = rbase + s * 16 - colbase;
    tdiag[s] = (d >= 0 && d < 512) ? (d >> 4) : -1;
  }

  const unsigned short* bbase = Xb + (size_t)(colbase + l16) * DIM + quad * 8;
  const float* sqp = sqv + colbase + l16;
  const int*   tgp = tgt + colbase + l16;

  // ---- sweep 1: per-lane two smallest vals per row; 2 tiles per iteration
  float m1[2][4], m2[2][4];
#pragma unroll
  for (int s = 0; s < 2; s++)
#pragma unroll
    for (int r = 0; r < 4; r++) { m1[s][r] = BIG; m2[s][r] = BIG; }
  for (int t = 0; t < NT; t += 2) {
    const unsigned short* p0 = bbase + (size_t)t * (16 * DIM);
    bf16x8 b0[4], b1[4];
#pragma unroll
    for (int kb = 0; kb < 4; kb++) {
      b0[kb] = *(const bf16x8*)(p0 + kb * 32);
      b1[kb] = *(const bf16x8*)(p0 + 16 * DIM + kb * 32);
    }
    const float sq0 = sqp[t * 16], sq1 = sqp[(t + 1) * 16];
    f32x4 a00 = {0.f,0.f,0.f,0.f}, a10 = {0.f,0.f,0.f,0.f};
    f32x4 a01 = {0.f,0.f,0.f,0.f}, a11 = {0.f,0.f,0.f,0.f};
#pragma unroll
    for (int kb = 0; kb < 4; kb++) {
      a00 = __builtin_amdgcn_mfma_f32_16x16x32_bf16(afrag[0][kb], b0[kb], a00, 0, 0, 0);
      a10 = __builtin_amdgcn_mfma_f32_16x16x32_bf16(afrag[1][kb], b0[kb], a10, 0, 0, 0);
      a01 = __builtin_amdgcn_mfma_f32_16x16x32_bf16(afrag[0][kb], b1[kb], a01, 0, 0, 0);
      a11 = __builtin_amdgcn_mfma_f32_16x16x32_bf16(afrag[1][kb], b1[kb], a11, 0, 0, 0);
    }
#pragma unroll
    for (int s = 0; s < 2; s++) {
#pragma unroll
      for (int r = 0; r < 4; r++) {
        float v0 = fmaf(-2.0f, (s ? a10[r] : a00[r]), sq0);
        float v1 = fmaf(-2.0f, (s ? a11[r] : a01[r]), sq1);
        if (t == tdiag[s] && l16 == quad * 4 + r) v0 = BIG;
        if (t + 1 == tdiag[s] && l16 == quad * 4 + r) v1 = BIG;
        m2[s][r] = fminf(m2[s][r], fmaxf(m1[s][r], v0));
        m1[s][r] = fminf(m1[s][r], v0);
        m2[s][r] = fminf(m2[s][r], fmaxf(m1[s][r], v1));
        m1[s][r] = fminf(m1[s][r], v1);
      }
    }
  }
  // publish min2: per row 4 waves x 16 lanes x 2 = 128 candidates (val-space)
#pragma unroll
  for (int s = 0; s < 2; s++)
#pragma unroll
    for (int r = 0; r < 4; r++) {
      int row = s * 16 + quad * 4 + r;
      sh[row * 128 + w * 32 + l16 * 2] = m1[s][r];
      sh[row * 128 + w * 32 + l16 * 2 + 1] = m2[s][r];
    }
  __syncthreads();

  // U[row] = 17th smallest of the 128-candidate subset (radix-select; >= quarter t17)
  for (int ri = 0; ri < 8; ri++) {
    int row = w * 8 + ri;
    float v17 = kth17_2(sh[row * 128 + lane], sh[row * 128 + 64 + lane]);
    if (lane == 0) Uv[row] = v17;
  }
  __syncthreads();
  float Ur[2][4];
#pragma unroll
  for (int s = 0; s < 2; s++)
#pragma unroll
    for (int r = 0; r < 4; r++) Ur[s][r] = Uv[s * 16 + quad * 4 + r];
  if (lane < ROWS) cnt[w][lane] = 0;   // wave-local; ordered before this wave's appends

  // ---- sweep 2: append val <= U (encode d2 = val + sqi, flag in sign bit)
  for (int t = 0; t < NT; t += 2) {
    const unsigned short* p0 = bbase + (size_t)t * (16 * DIM);
    bf16x8 b0[4], b1[4];
#pragma unroll
    for (int kb = 0; kb < 4; kb++) {
      b0[kb] = *(const bf16x8*)(p0 + kb * 32);
      b1[kb] = *(const bf16x8*)(p0 + 16 * DIM + kb * 32);
    }
    const float sq0 = sqp[t * 16], sq1 = sqp[(t + 1) * 16];
    const int tj0 = tgp[t * 16], tj1 = tgp[(t + 1) * 16];
    f32x4 a00 = {0.f,0.f,0.f,0.f}, a10 = {0.f,0.f,0.f,0.f};
    f32x4 a01 = {0.f,0.f,0.f,0.f}, a11 = {0.f,0.f,0.f,0.f};
#pragma unroll
    for (int kb = 0; kb < 4; kb++) {
      a00 = __builtin_amdgcn_mfma_f32_16x16x32_bf16(afrag[0][kb], b0[kb], a00, 0, 0, 0);
      a10 = __builtin_amdgcn_mfma_f32_16x16x32_bf16(afrag[1][kb], b0[kb], a10, 0, 0, 0);
      a01 = __builtin_amdgcn_mfma_f32_16x16x32_bf16(afrag[0][kb], b1[kb], a01, 0, 0, 0);
      a11 = __builtin_amdgcn_mfma_f32_16x16x32_bf16(afrag[1][kb], b1[kb], a11, 0, 0, 0);
    }
    float v0[2][4], v1[2][4]; bool any = false;
#pragma unroll
    for (int s = 0; s < 2; s++) {
#pragma unroll
      for (int r = 0; r < 4; r++) {
        float x0 = fmaf(-2.0f, (s ? a10[r] : a00[r]), sq0);
        float x1 = fmaf(-2.0f, (s ? a11[r] : a01[r]), sq1);
        if (t == tdiag[s] && l16 == quad * 4 + r) x0 = BIG;
        if (t + 1 == tdiag[s] && l16 == quad * 4 + r) x1 = BIG;
        v0[s][r] = x0; v1[s][r] = x1;
        any |= (x0 <= Ur[s][r]) | (x1 <= Ur[s][r]);
      }
    }
    if (__any(any)) {
#pragma unroll
      for (int s = 0; s < 2; s++) {
#pragma unroll
        for (int r = 0; r < 4; r++) {
          const int rl = s * 16 + quad * 4 + r;
          if (v0[s][r] <= Ur[s][r]) {
            int pos = atomicAdd(&cnt[w][rl], 1);
            if (pos < CAPW) {
              unsigned enc = __float_as_uint(fmaxf(v0[s][r] + sqi[s][r], 0.0f));
              if (tj0 == ti[s][r]) enc |= 0x80000000u;
              sh[(w * ROWS + rl) * CAPW + pos] = __uint_as_float(enc);
            }
          }
          if (v1[s][r] <= Ur[s][r]) {
            int pos = atomicAdd(&cnt[w][rl], 1);
            if (pos < CAPW) {
              unsigned enc = __float_as_uint(fmaxf(v1[s][r] + sqi[s][r], 0.0f));
              if (tj1 == ti[s][r]) enc |= 0x80000000u;
              sh[(w * ROWS + rl) * CAPW + pos] = __uint_as_float(enc);
            }
          }
        }
      }
    }
  }
  __syncthreads();

  // ---- finalize: raw-copy candidate lists (common) or 17-extract (overflow, rare)
  for (int rl = 0; rl < ROWS; rl++) {
    const int c0 = min(cnt[0][rl], CAPW), c1 = min(cnt[1][rl], CAPW),
              c2 = min(cnt[2][rl], CAPW), c3 = min(cnt[3][rl], CAPW);
    const int tot = c0 + c1 + c2 + c3;
    const int grow = rbase + rl;
    float* srow = scr + (size_t)grow * (4 * SEG) + quarter * SEG;
    if (tot <= SEG) {
      const int pre = (w > 0 ? c0 : 0) + (w > 1 ? c1 : 0) + (w > 2 ? c2 : 0);
      const int myc = (w == 0) ? c0 : ((w == 1) ? c1 : ((w == 2) ? c2 : c3));
      if (lane < myc) srow[pre + lane] = sh[(w * ROWS + rl) * CAPW + lane];
      if (tid == 0) cscr[grow * 4 + quarter] = tot;
    } else if (w == (rl & 3)) {
      float e[4]; int m[4];
#pragma unroll
      for (int ww = 0; ww < 4; ww++) {
        int n = min(cnt[ww][rl], CAPW);
        if (lane < n) {
          unsigned u = __float_as_uint(sh[(ww * ROWS + rl) * CAPW + lane]);
          m[ww] = (int)(u >> 31); e[ww] = __uint_as_float(u & 0x7fffffffu);
        } else { e[ww] = BIG; m[ww] = 0; }
      }
      for (int round = 0; round < KSEL; round++) {
        float v = e[0]; int idx = lane;
        if (e[1] < v) { v = e[1]; idx = lane | (1 << 6); }
        if (e[2] < v) { v = e[2]; idx = lane | (2 << 6); }
        if (e[3] < v) { v = e[3]; idx = lane | (3 << 6); }
#pragma unroll
        for (int off = 32; off; off >>= 1) {
          float ov = __shfl_xor(v, off);
          int   oi = __shfl_xor(idx, off);
          if (ov < v || (ov == v && oi < idx)) { v = ov; idx = oi; }
        }
        if ((idx & 63) == lane) {
          int s = idx >> 6;
          unsigned ub = __float_as_uint(e[s]);
          if (m[s]) ub |= 0x80000000u;
          srow[round] = __uint_as_float(ub);
          e[s] = BIG;
        }
      }
      if (lane == 0) cscr[grow * 4 + quarter] = KSEL;
    }
  }
}

// ---- per-row merge of 4 quarter-lists (<=128 candidates) + loss epilogue.
// NO fences, NO global atomics: per-block partials to pacc (plain stores).
__global__ __launch_bounds__(256) void knn_merge(
    const float* __restrict__ scr, const int* __restrict__ cscr,
    const float* __restrict__ sqv, const int* __restrict__ tgt,
    const int* __restrict__ ccount, const int* __restrict__ j0a,
    const int* __restrict__ j1a, const float* __restrict__ X32,
    float* __restrict__ pacc) {
  __shared__ float blockAcc[4];
  const int tid = threadIdx.x;
  const int w = tid >> 6;
  const int lane = tid & 63;
  if (tid < 4) blockAcc[tid] = 0.0f;
  __syncthreads();
  for (int ri = 0; ri < 4; ri++) {
    const int grow = blockIdx.x * 16 + w * 4 + ri;
    const float* srow = scr + (size_t)grow * (4 * SEG);
    const int ca = cscr[grow * 4 + (lane >> 5)];
    const int cb = cscr[grow * 4 + 2 + (lane >> 5)];
    const int li = lane & 31;
    float e0 = BIG, e1 = BIG; int mm0 = 0, mm1 = 0;
    if (li < ca) {
      unsigned u = __float_as_uint(srow[(lane >> 5) * SEG + li]);
      mm0 = (int)(u >> 31); e0 = __uint_as_float(u & 0x7fffffffu);
    }
    if (li < cb) {
      unsigned u = __float_as_uint(srow[(2 + (lane >> 5)) * SEG + li]);
      mm1 = (int)(u >> 31); e1 = __uint_as_float(u & 0x7fffffffu);
    }
    // exact 17th smallest of the union (radix-select)
    const float t17 = kth17_2(e0, e1);
    bool s0 = (e0 < t17), s1 = (e1 < t17);                // strict, matches reference
    float x0 = s0 ? expf(-sqrtf(fmaxf(e0, 1e-12f))) : 0.0f;
    float x1 = s1 ? expf(-sqrtf(fmaxf(e1, 1e-12f))) : 0.0f;
    float pls = (s0 && mm0 ? x0 : 0.0f) + (s1 && mm1 ? x1 : 0.0f);
    float nls = (s0 && !mm0 ? x0 : 0.0f) + (s1 && !mm1 ? x1 : 0.0f);
    int cpn = ((int)(s0 && mm0) + (int)(s1 && mm1)) * 65536 +
              ((int)(s0 && !mm0) + (int)(s1 && !mm1));
#pragma unroll
    for (int off = 32; off; off >>= 1) {
      pls += __shfl_xor(pls, off); nls += __shfl_xor(nls, off);
      cpn += __shfl_xor(cpn, off);
    }
    const int cp = cpn >> 16, cn = cpn & 0xffff;
    const int c = tgt[grow];
    const int ncl = ccount[c];
    const bool valid = (ncl > 1) && (ncl < NPTS);
    if (valid) {
      float pos_eff;
      if (cp == 0) {
        const int jf = (grow == j0a[c]) ? j1a[c] : j0a[c];
        const float* xi = X32 + (size_t)grow * DIM;
        const float* xj = X32 + (size_t)jf * DIM;
        float pp = xi[lane] * xj[lane] + xi[lane + 64] * xj[lane + 64];
#pragma unroll
        for (int off = 32; off; off >>= 1) pp += __shfl_xor(pp, off);
        const float fb2 = sqv[grow] + sqv[jf] - 2.0f * pp;
        pos_eff = expf(-sqrtf(fmaxf(fb2, 1e-12f)));
      } else {
        pos_eff = pls;
      }
      if (lane == 0) {
        const float loss_i = -logf(pos_eff / (pos_eff + nls));
        const int cpa = (cp == 0) ? 1 : cp;
        atomicAdd(&blockAcc[0], loss_i);
        atomicAdd(&blockAcc[1], (cpa > cn) ? 1.0f : 0.0f);
        atomicAdd(&blockAcc[2], (float)cp);
        atomicAdd(&blockAcc[3], (float)cn);
      }
    }
  }
  __syncthreads();
  if (tid < 4) pacc[blockIdx.x * 4 + tid] = blockAcc[tid];
}

// ---- final reduction: 1 block sums 512 x 4 partials, writes out
__global__ void fin(const float* __restrict__ pacc, float* __restrict__ out) {
  __shared__ float red[256];
  const int tid = threadIdx.x;
  const int c = tid & 3, b0 = tid >> 2;
  float s = 0.0f;
  for (int b = b0; b < MBLK; b += 64) s += pacc[b * 4 + c];
  red[tid] = s;
  __syncthreads();
  if (tid < 4) {
    float t = 0.0f;
    for (int i = tid; i < 256; i += 4) t += red[i];
    out[tid] = t * (1.0f / (float)NPTS);
  }
}

extern "C" void kernel_launch(void* const* d_in, const int* in_sizes, int n_in,
                              void* d_out, int out_size, void* d_ws, size_t ws_size,
                              hipStream_t stream) {
  const float* X = (const float*)d_in[0];
  const long long* targets = (const long long*)d_in[1];
  float* out = (float*)d_out;

  char* ws = (char*)d_ws;
  unsigned short* Xb = (unsigned short*)ws;                        // 2 MiB
  float* sqv    = (float*)   (ws + (2u << 20));                    // 32 KiB
  int*   tgt    = (int*)     (ws + (2u << 20) + (32u << 10));      // 32 KiB
  int*   ccount = (int*)     (ws + (2u << 20) + (64u << 10));      // 512 B
  int*   j0a    = (int*)     (ws + (2u << 20) + (65u << 10));      // 512 B
  int*   j1a    = (int*)     (ws + (2u << 20) + (66u << 10));      // 512 B
  float* pacc   = (float*)   (ws + (2u << 20) + (68u << 10));      // 8 KiB (512 x 4)
  float* scr = (float*)(ws + (2u << 20) + (128u << 10));           // 8192*4*SEG*4 = 4 MiB
  int* cscr  = (int*)  (ws + (2u << 20) + (128u << 10) + (size_t)NPTS * 4 * SEG * 4); // 128 KiB

  prep<<<2049, 256, 0, stream>>>(X, targets, Xb, sqv, tgt, ccount, j0a, j1a);
  knn_main<<<1024, 256, 0, stream>>>(Xb, sqv, tgt, scr, cscr);
  knn_merge<<<MBLK, 256, 0, stream>>>(scr, cscr, sqv, tgt, ccount, j0a, j1a, X, pacc);
  fin<<<1, 256, 0, stream>>>(pacc, out);
}